// Round 1
// baseline (2387.806 us; speedup 1.0000x reference)
//
#include <hip/hip_runtime.h>
#include <hip/hip_bf16.h>

// KeySelect2: conv_bn_relu(1024->128) x2, 9x9 local attention weighting,
// subtract, conv_bn_relu(128->128), global avg pool, fc(128->10->1).
// Round 1: correct fp32 baseline. Conv weights repacked to [ic][kh][kw][oc]
// so weight reads are wave-uniform (scalar loads); x staged through LDS.

#define B_ 4
#define H_ 64
#define W_ 64
#define CM_ 128   // C_RED

// ---------------- weight repack: [oc][ic][3][3] -> [ic*9+kh*3+kw][oc] -------
__global__ void repack_kernel(const float* __restrict__ w, float* __restrict__ wt,
                              int cin) {
  int i = blockIdx.x * 256 + threadIdx.x;
  int total = CM_ * cin * 9;
  if (i >= total) return;
  int oc = i / (cin * 9);
  int rem = i % (cin * 9);
  wt[(size_t)rem * CM_ + oc] = w[i];
}

// ---------------- 3x3 conv, CIN -> 128, NCHW ------------------------------
// grid: (B*H, 2) ; block 256 (4 waves). Wave wv handles ocs [ocTile*64+wv*16, +16).
// Lane = output column w. Weights read at wave-uniform addresses (s_load).
template <int CIN>
__global__ __launch_bounds__(256, 2)
void conv3x3_kernel(const float* __restrict__ x,   // [B,CIN,64,64]
                    const float* __restrict__ wt,  // [CIN*9,128]
                    float* __restrict__ y) {       // [B,128,64,64]
  constexpr int IC_BLK = 16;
  __shared__ float lx[IC_BLK][3][68];
  int bh = blockIdx.x;
  int b = bh >> 6, h = bh & 63;
  int tid = threadIdx.x;
  int lane = tid & 63;
  int wv = __builtin_amdgcn_readfirstlane(tid >> 6);
  int oc0 = blockIdx.y * 64 + wv * 16;

  float acc[16];
#pragma unroll
  for (int i = 0; i < 16; i++) acc[i] = 0.f;

  const float* xb = x + (size_t)b * CIN * 4096;

  for (int icc = 0; icc < CIN; icc += IC_BLK) {
    __syncthreads();  // previous compute done before restage
    // stage x chunk: rows h-1..h+1, cols -1..66 (zero pad), idx j = col+1
    for (int e = tid; e < IC_BLK * 3 * 68; e += 256) {
      int ic = e / (3 * 68);
      int rem = e % (3 * 68);
      int r = rem / 68;
      int j = rem % 68;
      int row = h + r - 1;
      float v = 0.f;
      if (row >= 0 && row < 64 && j >= 1 && j <= 64)
        v = xb[(size_t)(icc + ic) * 4096 + row * 64 + (j - 1)];
      lx[ic][r][j] = v;
    }
    __syncthreads();

    const float* wp = wt + (size_t)icc * 9 * CM_ + oc0;
#pragma unroll 2
    for (int ic = 0; ic < IC_BLK; ic++) {
#pragma unroll
      for (int r = 0; r < 3; r++) {
        float x0 = lx[ic][r][lane];      // kw=0 -> col w-1
        float x1 = lx[ic][r][lane + 1];  // kw=1 -> col w
        float x2 = lx[ic][r][lane + 2];  // kw=2 -> col w+1
        const float* wrow = wp + (ic * 9 + r * 3) * CM_;
#pragma unroll
        for (int j = 0; j < 16; j++) {
          acc[j] = fmaf(x0, wrow[j], acc[j]);
          acc[j] = fmaf(x1, wrow[CM_ + j], acc[j]);
          acc[j] = fmaf(x2, wrow[2 * CM_ + j], acc[j]);
        }
      }
    }
  }

  float* yp = y + ((size_t)b * CM_ + oc0) * 4096 + h * 64 + lane;
#pragma unroll
  for (int j = 0; j < 16; j++) yp[(size_t)j * 4096] = acc[j];
}

// ---------------- BN stats: per channel over (B,H,W) -> (scale, shift) -----
__global__ void bnstats_kernel(const float* __restrict__ y, const float* __restrict__ g,
                               const float* __restrict__ bt, float2* __restrict__ scsh) {
  int c = blockIdx.x;
  int tid = threadIdx.x;
  float s = 0.f, s2 = 0.f;
  for (int b = 0; b < B_; b++) {
    const float4* p = (const float4*)(y + ((size_t)(b * CM_) + c) * 4096);
    for (int i = tid; i < 1024; i += 256) {
      float4 v = p[i];
      s += v.x + v.y + v.z + v.w;
      s2 += v.x * v.x + v.y * v.y + v.z * v.z + v.w * v.w;
    }
  }
  for (int off = 32; off > 0; off >>= 1) {
    s += __shfl_down(s, off);
    s2 += __shfl_down(s2, off);
  }
  __shared__ float rs[4], rq[4];
  if ((tid & 63) == 0) { rs[tid >> 6] = s; rq[tid >> 6] = s2; }
  __syncthreads();
  if (tid == 0) {
    float S = rs[0] + rs[1] + rs[2] + rs[3];
    float Q = rq[0] + rq[1] + rq[2] + rq[3];
    float mean = S * (1.f / 16384.f);
    float var = Q * (1.f / 16384.f) - mean * mean;
    float sc = g[c] * rsqrtf(var + 1e-5f);
    scsh[c] = make_float2(sc, bt[c] - mean * sc);
  }
}

// ---------------- local weighting + BN/ReLU + subtract (in place on y4) ----
// out[b,c,h,w] = sum_{dh,dw} atten[b,h,w,dh*9+dw]*relu(bn1(y1))[b,c,h+dh-4,w+dw-4]
//               - relu(bn4(y4))[b,c,h,w]
// grid: (B*H, 8 c-tiles of 16); block 256. Wave wv handles c = c0+wv*4..+3.
__global__ __launch_bounds__(256, 2)
void localw_kernel(const float* __restrict__ y1, const float2* __restrict__ scsh1,
                   float* y4d, const float2* __restrict__ scsh4,
                   const float* __restrict__ atten) {
  __shared__ float at[81][65];     // transposed: at[k][w]
  __shared__ float lk[16][9][72];  // lk[c][r][j], j = col+4
  int bh = blockIdx.x;
  int b = bh >> 6, h = bh & 63;
  int c0 = blockIdx.y * 16;
  int tid = threadIdx.x;

  const float* ap = atten + ((size_t)b * 4096 + h * 64) * 81;
  for (int e = tid; e < 64 * 81; e += 256) {
    int w_ = e / 81, k = e % 81;
    at[k][w_] = ap[w_ * 81 + k];
  }
  for (int e = tid; e < 16 * 9 * 72; e += 256) {
    int c = e / (9 * 72);
    int rem = e % (9 * 72);
    int r = rem / 72;
    int j = rem % 72;
    int row = h + r - 4;
    int col = j - 4;
    float v = 0.f;
    if (row >= 0 && row < 64 && col >= 0 && col < 64) {
      float2 ss = scsh1[c0 + c];
      v = fmaxf(0.f, y1[((size_t)(b * CM_) + c0 + c) * 4096 + row * 64 + col] * ss.x + ss.y);
    }
    lk[c][r][j] = v;
  }
  __syncthreads();

  int lane = tid & 63;
  int wv = tid >> 6;
  float acc[4] = {0.f, 0.f, 0.f, 0.f};
  for (int r = 0; r < 9; r++) {
    float a[9];
#pragma unroll
    for (int dw = 0; dw < 9; dw++) a[dw] = at[r * 9 + dw][lane];
#pragma unroll
    for (int cc = 0; cc < 4; cc++) {
      int c = wv * 4 + cc;
#pragma unroll
      for (int dw = 0; dw < 9; dw++)
        acc[cc] = fmaf(a[dw], lk[c][r][lane + dw], acc[cc]);
    }
  }
#pragma unroll
  for (int cc = 0; cc < 4; cc++) {
    int c = c0 + wv * 4 + cc;
    size_t gi = ((size_t)(b * CM_) + c) * 4096 + h * 64 + lane;
    float2 ss4 = scsh4[c];
    float lnk = fmaxf(0.f, y4d[gi] * ss4.x + ss4.y);
    y4d[gi] = acc[cc] - lnk;  // in place: only this thread touches gi
  }
}

// ---------------- global avg pool with BN+ReLU ----------------------------
__global__ void pool_kernel(const float* __restrict__ y, const float2* __restrict__ scsh,
                            float* __restrict__ pooled) {
  int bc = blockIdx.x;  // b*128+c
  int c = bc & 127;
  float2 ss = scsh[c];
  const float4* p = (const float4*)(y + (size_t)bc * 4096);
  float s = 0.f;
  for (int i = threadIdx.x; i < 1024; i += 256) {
    float4 v = p[i];
    s += fmaxf(0.f, v.x * ss.x + ss.y) + fmaxf(0.f, v.y * ss.x + ss.y) +
         fmaxf(0.f, v.z * ss.x + ss.y) + fmaxf(0.f, v.w * ss.x + ss.y);
  }
  for (int off = 32; off > 0; off >>= 1) s += __shfl_down(s, off);
  __shared__ float rs[4];
  if ((threadIdx.x & 63) == 0) rs[threadIdx.x >> 6] = s;
  __syncthreads();
  if (threadIdx.x == 0) pooled[bc] = (rs[0] + rs[1] + rs[2] + rs[3]) * (1.f / 4096.f);
}

// ---------------- fc1 + fc2 -----------------------------------------------
__global__ void fc_kernel(const float* __restrict__ pooled, const float* __restrict__ fc1w,
                          const float* __restrict__ fc1b, const float* __restrict__ fc2w,
                          const float* __restrict__ fc2b, float* __restrict__ out) {
  int lane = threadIdx.x;  // 64 threads
  float p[B_][10];
#pragma unroll
  for (int b = 0; b < B_; b++)
#pragma unroll
    for (int j = 0; j < 10; j++) p[b][j] = 0.f;
  for (int c = lane; c < CM_; c += 64) {
#pragma unroll
    for (int b = 0; b < B_; b++) {
      float pv = pooled[b * CM_ + c];
#pragma unroll
      for (int j = 0; j < 10; j++) p[b][j] = fmaf(pv, fc1w[j * CM_ + c], p[b][j]);
    }
  }
  for (int off = 32; off > 0; off >>= 1)
#pragma unroll
    for (int b = 0; b < B_; b++)
#pragma unroll
      for (int j = 0; j < 10; j++) p[b][j] += __shfl_down(p[b][j], off);
  if (lane == 0) {
    for (int b = 0; b < B_; b++) {
      float o = fc2b[0];
      for (int j = 0; j < 10; j++) o += fc2w[j] * (p[b][j] + fc1b[j]);
      out[b] = o;
    }
  }
}

extern "C" void kernel_launch(void* const* d_in, const int* in_sizes, int n_in,
                              void* d_out, int out_size, void* d_ws, size_t ws_size,
                              hipStream_t stream) {
  const float* low_key    = (const float*)d_in[0];
  const float* low_nonkey = (const float*)d_in[1];
  const float* atten      = (const float*)d_in[2];
  const float* w1  = (const float*)d_in[3];
  const float* g1  = (const float*)d_in[4];
  const float* b1  = (const float*)d_in[5];
  const float* w4  = (const float*)d_in[6];
  const float* g4  = (const float*)d_in[7];
  const float* b4  = (const float*)d_in[8];
  const float* w5  = (const float*)d_in[9];
  const float* g5  = (const float*)d_in[10];
  const float* b5  = (const float*)d_in[11];
  const float* fc1w = (const float*)d_in[12];
  const float* fc1b = (const float*)d_in[13];
  const float* fc2w = (const float*)d_in[14];
  const float* fc2b = (const float*)d_in[15];

  float* ws = (float*)d_ws;
  float* wt1 = ws;                    // 1024*9*128 = 1179648
  float* wt4 = wt1 + 1179648;         // 1179648
  float* wt5 = wt4 + 1179648;         // 128*9*128 = 147456
  float* y1  = wt5 + 147456;          // 2097152  (also y5 later)
  float* y4  = y1 + 2097152;          // 2097152  (also d = trans - lnk, in place)
  float2* scsh1 = (float2*)(y4 + 2097152);
  float2* scsh4 = scsh1 + CM_;
  float2* scsh5 = scsh4 + CM_;
  float* pooled = (float*)(scsh5 + CM_);  // B*128
  float* out = (float*)d_out;

  repack_kernel<<<4608, 256, 0, stream>>>(w1, wt1, 1024);
  repack_kernel<<<4608, 256, 0, stream>>>(w4, wt4, 1024);
  repack_kernel<<<576, 256, 0, stream>>>(w5, wt5, 128);

  conv3x3_kernel<1024><<<dim3(256, 2), 256, 0, stream>>>(low_key, wt1, y1);
  bnstats_kernel<<<128, 256, 0, stream>>>(y1, g1, b1, scsh1);

  conv3x3_kernel<1024><<<dim3(256, 2), 256, 0, stream>>>(low_nonkey, wt4, y4);
  bnstats_kernel<<<128, 256, 0, stream>>>(y4, g4, b4, scsh4);

  localw_kernel<<<dim3(256, 8), 256, 0, stream>>>(y1, scsh1, y4, scsh4, atten);

  conv3x3_kernel<128><<<dim3(256, 2), 256, 0, stream>>>(y4, wt5, y1);  // y1 := y5
  bnstats_kernel<<<128, 256, 0, stream>>>(y1, g5, b5, scsh5);

  pool_kernel<<<512, 256, 0, stream>>>(y1, scsh5, pooled);
  fc_kernel<<<1, 64, 0, stream>>>(pooled, fc1w, fc1b, fc2w, fc2b, out);
}

// Round 2
// 447.858 us; speedup vs baseline: 5.3316x; 5.3316x over previous
//
#include <hip/hip_runtime.h>
#include <hip/hip_bf16.h>

// KeySelect2 round 2: bf16 MFMA implicit-GEMM for all three convs.
// - xprep: x fp32 NCHW -> xt bf16 [b][kb][row][col][32ic], ic-units XOR-swizzled
//   by (col>>1)&3 so conv B-fragment ds_read_b128 is bank-conflict-free.
// - wprep: w OIHW fp32 -> wpk bf16 [kb][tap][oc][32ic] (A-frags = 1KB coalesced).
// - convm: M=64 x N=128(row-pair) per block, K via LDS double-buffer filled by
//   global_load_lds(16B); 16x16x32 bf16 MFMA; A-frags double-buffered in regs.
// - localw writes conv5's input directly in xt layout (bf16), skipping fp32 d.

#define B_ 4
#define CM_ 128

typedef __attribute__((ext_vector_type(8))) short short8;
typedef __attribute__((ext_vector_type(4))) float floatx4;
typedef __attribute__((address_space(3))) unsigned lds_as;
typedef __attribute__((address_space(1))) const unsigned glb_as;

__device__ inline short f2bf(float f) {
  union { float f; unsigned u; } v; v.f = f;
  unsigned r = v.u + 0x7fff + ((v.u >> 16) & 1);  // RNE
  return (short)(r >> 16);
}

// ---------------- weight prepack: [oc][ic][3][3] -> [kb][tap][oc][32] bf16 ---
__global__ void wprep_kernel(const float* __restrict__ w, short* __restrict__ wpk,
                             int cin) {
  int e = blockIdx.x * 256 + threadIdx.x;
  if (e >= cin * 9 * 128) return;
  int icb = e & 31;
  int oc = (e >> 5) & 127;
  int tap = (e >> 12) % 9;
  int kb = e / (32 * 128 * 9);
  wpk[e] = f2bf(w[((size_t)oc * cin + kb * 32 + icb) * 9 + tap]);
}

// ---------------- x prepack: NCHW fp32 -> [b][kb][row][col][unit^sw][8] bf16 --
template <int KB>
__global__ void xprep_kernel(const float* __restrict__ x, short* __restrict__ xt) {
  int kb = blockIdx.x >> 4, rg = blockIdx.x & 15;
  int b = blockIdx.y;
  int row = rg * 4 + (threadIdx.x >> 6);
  int col = threadIdx.x & 63;
  const float* xs = x + (((size_t)b * (KB * 32) + kb * 32) * 64 + row) * 64 + col;
  short* xd = xt + ((((size_t)b * KB + kb) * 64 + row) * 64 + col) * 32;
  int sw = (col >> 1) & 3;
#pragma unroll
  for (int u = 0; u < 4; u++) {
    short8 pk;
#pragma unroll
    for (int j = 0; j < 8; j++) pk[j] = f2bf(xs[(size_t)(u * 8 + j) * 4096]);
    *(short8*)(xd + (u ^ sw) * 8) = pk;
  }
}

// ---------------- MFMA conv: xt [b][kb][row][col][32] x wpk -> y fp32 NCHW ----
// grid (128, 2): x = b*32 + h0/2 ; y = oc half. block 512 (8 waves).
// wave w: M-tile (w&3)*16 ocs, N row h0+(w>>2), 4 col-tiles of 16.
template <int KB>
__global__ __launch_bounds__(512, 2)
void convm_kernel(const short* __restrict__ xt, const short* __restrict__ wpk,
                  float* __restrict__ y) {
  __shared__ __attribute__((aligned(16))) short lx[16896];  // 2 x (4 rows x 66 cols x 32)
  int tid = threadIdx.x;
  int lane = tid & 63;
  int wv = tid >> 6;
  int n16 = lane & 15, quad = lane >> 4;
  int pb = blockIdx.x;
  int b = pb >> 5, h0 = (pb & 31) * 2;
  int oc0 = blockIdx.y * 64 + (wv & 3) * 16;
  int ng = wv >> 2;

  // zero pad columns (j=0, j=65) of every row, both buffers
  if (tid < 256) {
    int reg = tid >> 4, dw = tid & 15;
    int bu = reg >> 3, rr = (reg >> 1) & 3, cl = reg & 1;
    *(int*)(lx + bu * 8448 + rr * 2112 + (cl ? 65 : 0) * 32 + dw * 2) = 0;
  }
  // zero out-of-range boundary rows (never DMA'd)
  if (h0 == 0)
    for (int i = tid; i < 2112; i += 512) {
      int bu = i >= 1056; int o = i - bu * 1056;
      *((int*)lx + bu * 4224 + o) = 0;
    }
  if (h0 == 62)
    for (int i = tid; i < 2112; i += 512) {
      int bu = i >= 1056; int o = i - bu * 1056;
      *((int*)lx + bu * 4224 + 3 * 1056 + o) = 0;
    }

  // DMA one K-block (32 ic) slab: rows h0-1..h0+2, cols 0..63 -> LDS j=1..64
  auto dma = [&](int kb, int buf) {
#pragma unroll
    for (int t = 0; t < 2; t++) {
      int idx = wv * 2 + t;          // 16 chunks of 1KB
      int r = idx >> 2, cc = idx & 3;
      int row = h0 - 1 + r;
      if (row >= 0 && row < 64) {
        const short* src = xt + ((((size_t)b * KB + kb) * 64 + row) * 64 + cc * 16) * 32 + lane * 8;
        short* dst = lx + buf * 8448 + r * 2112 + (1 + cc * 16) * 32 + lane * 8;
        __builtin_amdgcn_global_load_lds((glb_as*)src, (lds_as*)dst, 16, 0, 0);
      }
    }
  };

  const short* wb = wpk + (size_t)(oc0 + n16) * 32 + quad * 8;
  short8 afr[9], afn[9];
  dma(0, 0);
#pragma unroll
  for (int t = 0; t < 9; t++) afr[t] = *(const short8*)(wb + t * 4096);

  floatx4 acc[4];
#pragma unroll
  for (int nt = 0; nt < 4; nt++) acc[nt] = (floatx4){0.f, 0.f, 0.f, 0.f};

  for (int kb = 0; kb < KB; kb++) {
    __syncthreads();  // compiler emits vmcnt(0) drain: DMA for kb complete
    if (kb + 1 < KB) {
      dma(kb + 1, (kb + 1) & 1);
      const short* wn = wb + (size_t)(kb + 1) * 36864;
#pragma unroll
      for (int t = 0; t < 9; t++) afn[t] = *(const short8*)(wn + t * 4096);
    }
    const short* lb = lx + (kb & 1) * 8448;
#pragma unroll
    for (int tap = 0; tap < 9; tap++) {
      int r = tap / 3, s = tap % 3;
      const short* lr = lb + (ng + r) * 2112;
#pragma unroll
      for (int nt = 0; nt < 4; nt++) {
        int c = nt * 16 + n16 + s - 1;          // source col, -1..64
        int uu = quad ^ ((c >> 1) & 3);         // bank swizzle (matches xprep)
        short8 bf = *(const short8*)(lr + (c + 1) * 32 + uu * 8);
        acc[nt] = __builtin_amdgcn_mfma_f32_16x16x32_bf16(afr[tap], bf, acc[nt], 0, 0, 0);
      }
    }
    if (kb + 1 < KB) {
#pragma unroll
      for (int t = 0; t < 9; t++) afr[t] = afn[t];
    }
  }

  int row = h0 + ng, col = lane & 15;
#pragma unroll
  for (int nt = 0; nt < 4; nt++)
#pragma unroll
    for (int rg = 0; rg < 4; rg++) {
      int oc = oc0 + quad * 4 + rg;  // D layout: row = quad*4+reg, col = lane&15
      y[(((size_t)b * CM_ + oc) * 64 + row) * 64 + nt * 16 + col] = acc[nt][rg];
    }
}

// ---------------- BN stats -------------------------------------------------
__global__ void bnstats_kernel(const float* __restrict__ y, const float* __restrict__ g,
                               const float* __restrict__ bt, float2* __restrict__ scsh) {
  int c = blockIdx.x;
  int tid = threadIdx.x;
  float s = 0.f, s2 = 0.f;
  for (int b = 0; b < B_; b++) {
    const float4* p = (const float4*)(y + ((size_t)(b * CM_) + c) * 4096);
    for (int i = tid; i < 1024; i += 256) {
      float4 v = p[i];
      s += v.x + v.y + v.z + v.w;
      s2 += v.x * v.x + v.y * v.y + v.z * v.z + v.w * v.w;
    }
  }
  for (int off = 32; off > 0; off >>= 1) {
    s += __shfl_down(s, off);
    s2 += __shfl_down(s2, off);
  }
  __shared__ float rs[4], rq[4];
  if ((tid & 63) == 0) { rs[tid >> 6] = s; rq[tid >> 6] = s2; }
  __syncthreads();
  if (tid == 0) {
    float S = rs[0] + rs[1] + rs[2] + rs[3];
    float Q = rq[0] + rq[1] + rq[2] + rq[3];
    float mean = S * (1.f / 16384.f);
    float var = Q * (1.f / 16384.f) - mean * mean;
    float sc = g[c] * rsqrtf(var + 1e-5f);
    scsh[c] = make_float2(sc, bt[c] - mean * sc);
  }
}

// ---------------- local weighting + subtract -> xt5 (bf16, conv5 layout) ----
__global__ __launch_bounds__(256, 2)
void localw_kernel(const float* __restrict__ y1, const float2* __restrict__ scsh1,
                   const float* __restrict__ y4, const float2* __restrict__ scsh4,
                   const float* __restrict__ atten, short* __restrict__ xt5) {
  __shared__ float at[81][65];
  __shared__ float lk[16][9][72];
  int bh = blockIdx.x;
  int b = bh >> 6, h = bh & 63;
  int c0 = blockIdx.y * 16;
  int tid = threadIdx.x;

  const float* ap = atten + ((size_t)b * 4096 + h * 64) * 81;
  for (int e = tid; e < 64 * 81; e += 256) {
    int w_ = e / 81, k = e % 81;
    at[k][w_] = ap[w_ * 81 + k];
  }
  for (int e = tid; e < 16 * 9 * 72; e += 256) {
    int c = e / (9 * 72);
    int rem = e % (9 * 72);
    int r = rem / 72;
    int j = rem % 72;
    int row = h + r - 4;
    int col = j - 4;
    float v = 0.f;
    if (row >= 0 && row < 64 && col >= 0 && col < 64) {
      float2 ss = scsh1[c0 + c];
      v = fmaxf(0.f, y1[((size_t)(b * CM_) + c0 + c) * 4096 + row * 64 + col] * ss.x + ss.y);
    }
    lk[c][r][j] = v;
  }
  __syncthreads();

  int lane = tid & 63;
  int wv = tid >> 6;
  float acc[4] = {0.f, 0.f, 0.f, 0.f};
  for (int r = 0; r < 9; r++) {
    float a[9];
#pragma unroll
    for (int dw = 0; dw < 9; dw++) a[dw] = at[r * 9 + dw][lane];
#pragma unroll
    for (int cc = 0; cc < 4; cc++) {
      int c = wv * 4 + cc;
#pragma unroll
      for (int dw = 0; dw < 9; dw++)
        acc[cc] = fmaf(a[dw], lk[c][r][lane + dw], acc[cc]);
    }
  }
#pragma unroll
  for (int cc = 0; cc < 4; cc++) {
    int c = c0 + wv * 4 + cc;
    float2 ss4 = scsh4[c];
    float lnk = fmaxf(0.f, y4[((size_t)(b * CM_) + c) * 4096 + h * 64 + lane] * ss4.x + ss4.y);
    float dv = acc[cc] - lnk;
    int icb = c & 31;
    int uu = (icb >> 3) ^ ((lane >> 1) & 3);
    xt5[((((size_t)b * 4 + (c >> 5)) * 64 + h) * 64 + lane) * 32 + uu * 8 + (icb & 7)] = f2bf(dv);
  }
}

// ---------------- global avg pool with BN+ReLU ----------------------------
__global__ void pool_kernel(const float* __restrict__ y, const float2* __restrict__ scsh,
                            float* __restrict__ pooled) {
  int bc = blockIdx.x;
  int c = bc & 127;
  float2 ss = scsh[c];
  const float4* p = (const float4*)(y + (size_t)bc * 4096);
  float s = 0.f;
  for (int i = threadIdx.x; i < 1024; i += 256) {
    float4 v = p[i];
    s += fmaxf(0.f, v.x * ss.x + ss.y) + fmaxf(0.f, v.y * ss.x + ss.y) +
         fmaxf(0.f, v.z * ss.x + ss.y) + fmaxf(0.f, v.w * ss.x + ss.y);
  }
  for (int off = 32; off > 0; off >>= 1) s += __shfl_down(s, off);
  __shared__ float rs[4];
  if ((threadIdx.x & 63) == 0) rs[threadIdx.x >> 6] = s;
  __syncthreads();
  if (threadIdx.x == 0) pooled[bc] = (rs[0] + rs[1] + rs[2] + rs[3]) * (1.f / 4096.f);
}

// ---------------- fc1 + fc2 -----------------------------------------------
__global__ void fc_kernel(const float* __restrict__ pooled, const float* __restrict__ fc1w,
                          const float* __restrict__ fc1b, const float* __restrict__ fc2w,
                          const float* __restrict__ fc2b, float* __restrict__ out) {
  int lane = threadIdx.x;
  float p[B_][10];
#pragma unroll
  for (int b = 0; b < B_; b++)
#pragma unroll
    for (int j = 0; j < 10; j++) p[b][j] = 0.f;
  for (int c = lane; c < CM_; c += 64) {
#pragma unroll
    for (int b = 0; b < B_; b++) {
      float pv = pooled[b * CM_ + c];
#pragma unroll
      for (int j = 0; j < 10; j++) p[b][j] = fmaf(pv, fc1w[j * CM_ + c], p[b][j]);
    }
  }
  for (int off = 32; off > 0; off >>= 1)
#pragma unroll
    for (int b = 0; b < B_; b++)
#pragma unroll
      for (int j = 0; j < 10; j++) p[b][j] += __shfl_down(p[b][j], off);
  if (lane == 0) {
    for (int b = 0; b < B_; b++) {
      float o = fc2b[0];
      for (int j = 0; j < 10; j++) o += fc2w[j] * (p[b][j] + fc1b[j]);
      out[b] = o;
    }
  }
}

extern "C" void kernel_launch(void* const* d_in, const int* in_sizes, int n_in,
                              void* d_out, int out_size, void* d_ws, size_t ws_size,
                              hipStream_t stream) {
  const float* low_key    = (const float*)d_in[0];
  const float* low_nonkey = (const float*)d_in[1];
  const float* atten      = (const float*)d_in[2];
  const float* w1  = (const float*)d_in[3];
  const float* g1  = (const float*)d_in[4];
  const float* b1  = (const float*)d_in[5];
  const float* w4  = (const float*)d_in[6];
  const float* g4  = (const float*)d_in[7];
  const float* b4  = (const float*)d_in[8];
  const float* w5  = (const float*)d_in[9];
  const float* g5  = (const float*)d_in[10];
  const float* b5  = (const float*)d_in[11];
  const float* fc1w = (const float*)d_in[12];
  const float* fc1b = (const float*)d_in[13];
  const float* fc2w = (const float*)d_in[14];
  const float* fc2b = (const float*)d_in[15];

  char* w8 = (char*)d_ws;
  short* wpk = (short*)w8;                                   // 2,359,296 B (max)
  short* xt  = (short*)(w8 + 2359296);                       // 33,554,432 B
  short* xt5 = (short*)(w8 + 2359296 + 33554432);            // 4,194,304 B
  float* y1  = (float*)(w8 + 2359296 + 33554432 + 4194304);  // 8,388,608 B
  float* y4  = y1 + 2097152;                                 // 8,388,608 B
  float2* scsh1 = (float2*)(y4 + 2097152);
  float2* scsh4 = scsh1 + CM_;
  float2* scsh5 = scsh4 + CM_;
  float* pooled = (float*)(scsh5 + CM_);
  float* out = (float*)d_out;

  // conv1 path
  wprep_kernel<<<4608, 256, 0, stream>>>(w1, wpk, 1024);
  xprep_kernel<32><<<dim3(512, 4), 256, 0, stream>>>(low_key, xt);
  convm_kernel<32><<<dim3(128, 2), 512, 0, stream>>>(xt, wpk, y1);
  bnstats_kernel<<<128, 256, 0, stream>>>(y1, g1, b1, scsh1);

  // conv4 path (reuses wpk/xt buffers — stream-ordered)
  wprep_kernel<<<4608, 256, 0, stream>>>(w4, wpk, 1024);
  xprep_kernel<32><<<dim3(512, 4), 256, 0, stream>>>(low_nonkey, xt);
  convm_kernel<32><<<dim3(128, 2), 512, 0, stream>>>(xt, wpk, y4);
  bnstats_kernel<<<128, 256, 0, stream>>>(y4, g4, b4, scsh4);

  // local weighting + subtract, emits conv5 input in xt layout
  localw_kernel<<<dim3(256, 8), 256, 0, stream>>>(y1, scsh1, y4, scsh4, atten, xt5);

  // conv5 path (output into y1 buffer)
  wprep_kernel<<<576, 256, 0, stream>>>(w5, wpk, 128);
  convm_kernel<4><<<dim3(128, 2), 512, 0, stream>>>(xt5, wpk, y1);
  bnstats_kernel<<<128, 256, 0, stream>>>(y1, g5, b5, scsh5);

  pool_kernel<<<512, 256, 0, stream>>>(y1, scsh5, pooled);
  fc_kernel<<<1, 64, 0, stream>>>(pooled, fc1w, fc1b, fc2w, fc2b, out);
}